// Round 4
// baseline (338.517 us; speedup 1.0000x reference)
//
#include <hip/hip_runtime.h>
#include <hip/hip_bf16.h>
#include <stdint.h>

typedef __attribute__((ext_vector_type(4))) float f32x4;
typedef __attribute__((ext_vector_type(8))) short s16x8;

#define BARRIER() __builtin_amdgcn_s_barrier()
#define WAITV4()  asm volatile("s_waitcnt vmcnt(4)" ::: "memory")
#define WAITV0()  asm volatile("s_waitcnt vmcnt(0)" ::: "memory")
#define LGKM0()   asm volatile("s_waitcnt lgkmcnt(0)" ::: "memory")
#define MFMA(a, b, c) __builtin_amdgcn_mfma_f32_16x16x32_bf16((a), (b), (c), 0, 0, 0)

__device__ __forceinline__ ushort f2bf(float f) {
  union { float f; uint32_t u; } v; v.f = f;
  uint32_t r = v.u + 0x7FFFu + ((v.u >> 16) & 1u);
  return (ushort)(r >> 16);
}

__device__ __forceinline__ void gload_lds16(const ushort* g, short* l) {
  __builtin_amdgcn_global_load_lds(
      (const __attribute__((address_space(1))) uint32_t*)g,
      (__attribute__((address_space(3))) uint32_t*)l, 16, 0, 0);
}

// bijective XCD chunk swizzle; valid when nwg % 8 == 0, q = nwg/8
__device__ __forceinline__ int xcd_swz(int flat, int q) {
  return (flat & 7) * q + (flat >> 3);
}

// Stage a 256x64 bf16 tile (rows row0.., cols k0..k0+63 of g[ld]) into LDS.
// LDS dest is linear (global_load_lds requirement); T2 swizzle done by
// permuting the GLOBAL source 16B-slot: phys(r,s) holds global(r, s ^ (r&7)).
__device__ __forceinline__ void stage256(const ushort* __restrict__ g, int ld,
                                         int row0, int k0, short* lbase, int tid) {
  const int w  = tid >> 6;
  const int l  = tid & 63;
  const int lr = l >> 3;                 // row within 8-row group (= row&7)
  const int ls = l & 7;                  // physical 16B slot
  const ushort* gp = g + (size_t)(row0 + lr) * ld + k0 + ((ls ^ lr) << 3);
  short* lp = lbase + l * 8;
#pragma unroll
  for (int i = 0; i < 4; ++i) {
    const int R0 = w * 32 + i * 8;
    gload_lds16(gp + (size_t)R0 * ld, lp + R0 * 64);
  }
}

// 256x256 tile GEMM core: A[M,K] * Bt[N,K]^T, bf16, fp32 acc.
// 512 thr = 8 waves (2M x 4N), wave = 128x64 out = 8x4 frags of 16x16x32.
// m201-style 4-phase/K-tile schedule: per phase {ds quadrant || stage issue,
// barrier, lgkm0, setprio+16 MFMA, barrier}; vmcnt(4) gate once per tile.
__device__ __forceinline__ void gemm_core(
    const ushort* __restrict__ A, int lda, const ushort* __restrict__ Bt, int ldb,
    int m0, int n0, int nk, short* lds, f32x4 acc[8][4])
{
  const int tid  = threadIdx.x;
  const int lane = tid & 63;
  const int wid  = tid >> 6;
  const int wr = wid >> 2, wc = wid & 3;
  const int fr = lane & 15, kg = lane >> 4;
  const int s0  = (kg ^ (fr & 7)) << 3;        // swizzled slot offset (shorts)
  const int aro = (wr * 128 + fr) * 64;
  const int bro = (wc * 64 + fr) * 64;

  short* const Abuf0 = lds;
  short* const Bbuf0 = lds + 16384;
  short* const Abuf1 = lds + 32768;
  short* const Bbuf1 = lds + 49152;

#pragma unroll
  for (int i = 0; i < 8; ++i)
#pragma unroll
    for (int j = 0; j < 4; ++j)
      acc[i][j] = (f32x4){0.f, 0.f, 0.f, 0.f};

  // prologue: A(0),B(0) into buf0, A(1) into buf1; drain tile0, keep A(1).
  stage256(A, lda, m0, 0, Abuf0, tid);
  stage256(Bt, ldb, n0, 0, Bbuf0, tid);
  if (nk > 1) { stage256(A, lda, m0, 64, Abuf1, tid); WAITV4(); }
  else        { WAITV0(); }
  BARRIER();

#pragma unroll 1
  for (int X = 0; X < nk; ++X) {
    short* const Ac = (X & 1) ? Abuf1 : Abuf0;
    short* const Bc = (X & 1) ? Bbuf1 : Bbuf0;
    short* const Bn = (X & 1) ? Bbuf0 : Bbuf1;

    s16x8 a[4][2], b01[2][2], b23[2][2];

    // ---- phase 1: (mi0-3 x ni0-1); stage B(X+1)
#pragma unroll
    for (int n = 0; n < 2; ++n) {
      b01[n][0] = *(const s16x8*)(Bc + bro + n * 1024 + s0);
      b01[n][1] = *(const s16x8*)(Bc + bro + n * 1024 + (s0 ^ 32));
    }
#pragma unroll
    for (int m = 0; m < 4; ++m) {
      a[m][0] = *(const s16x8*)(Ac + aro + m * 1024 + s0);
      a[m][1] = *(const s16x8*)(Ac + aro + m * 1024 + (s0 ^ 32));
    }
    if (X + 1 < nk) stage256(Bt, ldb, n0, (X + 1) * 64, Bn, tid);
    BARRIER(); LGKM0();
    __builtin_amdgcn_s_setprio(1);
#pragma unroll
    for (int m = 0; m < 4; ++m)
#pragma unroll
      for (int n = 0; n < 2; ++n) {
        acc[m][n] = MFMA(a[m][0], b01[n][0], acc[m][n]);
        acc[m][n] = MFMA(a[m][1], b01[n][1], acc[m][n]);
      }
    __builtin_amdgcn_s_setprio(0);
    BARRIER();

    // ---- phase 2: (mi0-3 x ni2-3)
#pragma unroll
    for (int n = 0; n < 2; ++n) {
      b23[n][0] = *(const s16x8*)(Bc + bro + (2 + n) * 1024 + s0);
      b23[n][1] = *(const s16x8*)(Bc + bro + (2 + n) * 1024 + (s0 ^ 32));
    }
    BARRIER(); LGKM0();
    __builtin_amdgcn_s_setprio(1);
#pragma unroll
    for (int m = 0; m < 4; ++m)
#pragma unroll
      for (int n = 0; n < 2; ++n) {
        acc[m][2 + n] = MFMA(a[m][0], b23[n][0], acc[m][2 + n]);
        acc[m][2 + n] = MFMA(a[m][1], b23[n][1], acc[m][2 + n]);
      }
    __builtin_amdgcn_s_setprio(0);
    BARRIER();

    // ---- phase 3: (mi4-7 x ni2-3)
#pragma unroll
    for (int m = 0; m < 4; ++m) {
      a[m][0] = *(const s16x8*)(Ac + aro + (4 + m) * 1024 + s0);
      a[m][1] = *(const s16x8*)(Ac + aro + (4 + m) * 1024 + (s0 ^ 32));
    }
    BARRIER(); LGKM0();
    __builtin_amdgcn_s_setprio(1);
#pragma unroll
    for (int m = 0; m < 4; ++m)
#pragma unroll
      for (int n = 0; n < 2; ++n) {
        acc[4 + m][2 + n] = MFMA(a[m][0], b23[n][0], acc[4 + m][2 + n]);
        acc[4 + m][2 + n] = MFMA(a[m][1], b23[n][1], acc[4 + m][2 + n]);
      }
    __builtin_amdgcn_s_setprio(0);
    BARRIER();

    // ---- phase 4: (mi4-7 x ni0-1); stage A(X+2) into Ac (A-half reads sealed
    // at ph3 lgkm0+barrier); gate: drain A(X+1),B(X+1), keep A(X+2) in flight.
    if (X + 2 < nk) stage256(A, lda, m0, (X + 2) * 64, Ac, tid);
    BARRIER();
    __builtin_amdgcn_s_setprio(1);
#pragma unroll
    for (int m = 0; m < 4; ++m)
#pragma unroll
      for (int n = 0; n < 2; ++n) {
        acc[4 + m][n] = MFMA(a[m][0], b01[n][0], acc[4 + m][n]);
        acc[4 + m][n] = MFMA(a[m][1], b01[n][1], acc[4 + m][n]);
      }
    __builtin_amdgcn_s_setprio(0);
    if (X + 2 < nk) { WAITV4(); } else { WAITV0(); }
    BARRIER();
  }
}

__global__ void cvt_x(const float* __restrict__ x, ushort* __restrict__ xb)
{
  const size_t i = (size_t)(blockIdx.x * 256 + threadIdx.x) * 4;
  const f32x4 t = *(const f32x4*)(x + i);
  uint2 pk;
  pk.x = (uint32_t)f2bf(t[0]) | ((uint32_t)f2bf(t[1]) << 16);
  pk.y = (uint32_t)f2bf(t[2]) | ((uint32_t)f2bf(t[3]) << 16);
  *(uint2*)(xb + i) = pk;
}

// wt[z][n][k] = bf16(w_z[k][n]);  z: 0=q_wei, 1=k_wei, 2=v_wei
__global__ void cvt_w(const float* __restrict__ kw, const float* __restrict__ qw,
                      const float* __restrict__ vw, ushort* __restrict__ wt)
{
  __shared__ float t[32][33];
  const float* w = (blockIdx.z == 0) ? qw : (blockIdx.z == 1) ? kw : vw;
  const int n0 = blockIdx.x * 32, k0 = blockIdx.y * 32;
  t[threadIdx.y][threadIdx.x] = w[(size_t)(k0 + threadIdx.y) * 1024 + n0 + threadIdx.x];
  __syncthreads();
  wt[(size_t)blockIdx.z * 1048576 + (size_t)(n0 + threadIdx.y) * 1024 + k0 + threadIdx.x] =
      f2bf(t[threadIdx.x][threadIdx.y]);
}

// N = 3072 (q|k|v), M = 16384. grid (12, 64).
__global__ __launch_bounds__(512) void gemm_qkv_impl(
    const ushort* __restrict__ xb, const ushort* __restrict__ wt,
    ushort* __restrict__ q, ushort* __restrict__ k, ushort* __restrict__ vT)
{
  extern __shared__ short lds[];
  const int nf = xcd_swz(blockIdx.x + 12 * blockIdx.y, 96);
  const int n0 = (nf % 12) * 256;
  const int m0 = (nf / 12) * 256;
  f32x4 acc[8][4];
  gemm_core(xb, 1024, wt, 1024, m0, n0, 16, lds, acc);

  const int lane = threadIdx.x & 63;
  const int wid = threadIdx.x >> 6;
  const int wr = wid >> 2, wc = wid & 3;
  const int q4 = (lane >> 4) << 2;
  const int fr = lane & 15;
  const int z  = n0 >> 10;                         // uniform per block
  const int cb = (n0 & 1023) + wc * 64 + fr;
  ushort* o = (z == 0) ? q : k;
#pragma unroll
  for (int mi = 0; mi < 8; ++mi)
#pragma unroll
    for (int ni = 0; ni < 4; ++ni)
#pragma unroll
      for (int j = 0; j < 4; ++j) {
        const int r = m0 + wr * 128 + mi * 16 + q4 + j;
        const int c = cb + ni * 16;
        const ushort hv = f2bf(acc[mi][ni][j]);
        if (z < 2) o[(size_t)r * 1024 + c] = hv;
        else       vT[((size_t)(r >> 11) * 1024 + c) * 2048 + (r & 2047)] = hv;
      }
}

// grid (8 kt, 8 qt, 8 b), 256^2 tiles, causal tile skip.
__global__ __launch_bounds__(512) void gemm_s(
    const ushort* __restrict__ q, const ushort* __restrict__ k, float* __restrict__ S)
{
  extern __shared__ short lds[];
  const int nf = xcd_swz(blockIdx.x + 8 * (blockIdx.y + 8 * blockIdx.z), 64);
  const int kt = nf & 7, qt = (nf >> 3) & 7, b = nf >> 6;
  if (kt > qt) return;  // causal: whole tile masked
  f32x4 acc[8][4];
  const ushort* qb = q + (size_t)b * (2048 * 1024);
  const ushort* kb = k + (size_t)b * (2048 * 1024);
  gemm_core(qb, 1024, kb, 1024, qt * 256, kt * 256, 16, lds, acc);

  float* Sb = S + (size_t)b * 4194304;
  const int lane = threadIdx.x & 63;
  const int wid = threadIdx.x >> 6;
  const int wr = wid >> 2, wc = wid & 3;
  const int r0 = qt * 256 + wr * 128 + ((lane >> 4) << 2);
  const int c0 = kt * 256 + wc * 64 + (lane & 15);
#pragma unroll
  for (int mi = 0; mi < 8; ++mi)
#pragma unroll
    for (int ni = 0; ni < 4; ++ni)
#pragma unroll
      for (int j = 0; j < 4; ++j)
        Sb[(size_t)(r0 + mi * 16 + j) * 2048 + (c0 + ni * 16)] = acc[mi][ni][j];
}

// one wave per row; reads S fp32, writes P bf16 in place (same row base).
__global__ __launch_bounds__(256) void softmax_k(float* __restrict__ S)
{
  const int row  = blockIdx.x * 4 + (threadIdx.x >> 6);
  const int lane = threadIdx.x & 63;
  const int L = (row & 2047) + 1;  // valid keys = query_index + 1
  float* srow = S + (size_t)row * 2048;
  float v[32];
#pragma unroll
  for (int it = 0; it < 8; ++it) {
    const int j0 = (it * 64 + lane) * 4;
    const f32x4 t = *(const f32x4*)(srow + j0);
#pragma unroll
    for (int u = 0; u < 4; ++u) v[it * 4 + u] = (j0 + u < L) ? t[u] : -1e30f;
  }
  float m = v[0];
#pragma unroll
  for (int i = 1; i < 32; ++i) m = fmaxf(m, v[i]);
#pragma unroll
  for (int off = 32; off > 0; off >>= 1) m = fmaxf(m, __shfl_xor(m, off));
  float sum = 0.f;
#pragma unroll
  for (int i = 0; i < 32; ++i) {
    const float e = (v[i] > -1e29f) ? __expf((v[i] - m) * 0.03125f) : 0.f;
    v[i] = e; sum += e;
  }
#pragma unroll
  for (int off = 32; off > 0; off >>= 1) sum += __shfl_xor(sum, off);
  const float rs = 1.f / sum;
  ushort* prow = (ushort*)srow;
#pragma unroll
  for (int it = 0; it < 8; ++it) {
    const int j0 = (it * 64 + lane) * 4;
    uint2 pk;
    pk.x = (uint32_t)f2bf(v[it*4+0] * rs) | ((uint32_t)f2bf(v[it*4+1] * rs) << 16);
    pk.y = (uint32_t)f2bf(v[it*4+2] * rs) | ((uint32_t)f2bf(v[it*4+3] * rs) << 16);
    *(uint2*)(prow + j0) = pk;
  }
}

// grid (4 ht, 8 qt, 8 b); K truncated causally to (qt+1)*256 keys.
__global__ __launch_bounds__(512) void gemm_pv(
    const ushort* __restrict__ P, const ushort* __restrict__ vT, float* __restrict__ out)
{
  extern __shared__ short lds[];
  const int nf = xcd_swz(blockIdx.x + 4 * (blockIdx.y + 8 * blockIdx.z), 32);
  const int ht = nf & 3, qt = (nf >> 2) & 7, b = nf >> 5;
  f32x4 acc[8][4];
  const ushort* Pb = P  + (size_t)b * (2048 * 4096);  // P rows stride 4096 elems
  const ushort* Vb = vT + (size_t)b * (1024 * 2048);
  gemm_core(Pb, 4096, Vb, 2048, qt * 256, ht * 256, (qt + 1) * 4, lds, acc);

  float* ob = out + (size_t)b * 2097152;
  const int lane = threadIdx.x & 63;
  const int wid = threadIdx.x >> 6;
  const int wr = wid >> 2, wc = wid & 3;
  const int r0 = qt * 256 + wr * 128 + ((lane >> 4) << 2);
  const int c0 = ht * 256 + wc * 64 + (lane & 15);
#pragma unroll
  for (int mi = 0; mi < 8; ++mi)
#pragma unroll
    for (int ni = 0; ni < 4; ++ni)
#pragma unroll
      for (int j = 0; j < 4; ++j)
        ob[(size_t)(r0 + mi * 16 + j) * 1024 + (c0 + ni * 16)] = acc[mi][ni][j];
}

extern "C" void kernel_launch(void* const* d_in, const int* in_sizes, int n_in,
                              void* d_out, int out_size, void* d_ws, size_t ws_size,
                              hipStream_t stream)
{
  const float* x  = (const float*)d_in[0];
  const float* kw = (const float*)d_in[1];
  const float* qw = (const float*)d_in[2];
  const float* vw = (const float*)d_in[3];
  float* out = (float*)d_out;
  char* ws = (char*)d_ws;

  ushort* xb = (ushort*)ws;                    // 32MB, aliases S (consumed before S written)
  float*  S  = (float*)ws;                     // 128MB fp32 scores; P bf16 written in place
  ushort* wt = (ushort*)(ws + 134217728);      // 6MB  transposed bf16 weights [z][n][k]
  ushort* q  = (ushort*)(ws + 140509184);      // 32MB
  ushort* k  = (ushort*)(ws + 174063616);      // 32MB
  ushort* vT = (ushort*)(ws + 207618048);      // 32MB [B][HS][T]

  const int LDSB = 131072;  // 128KB dynamic LDS
  hipFuncSetAttribute((const void*)gemm_qkv_impl, hipFuncAttributeMaxDynamicSharedMemorySize, LDSB);
  hipFuncSetAttribute((const void*)gemm_s,        hipFuncAttributeMaxDynamicSharedMemorySize, LDSB);
  hipFuncSetAttribute((const void*)gemm_pv,       hipFuncAttributeMaxDynamicSharedMemorySize, LDSB);

  cvt_x<<<16384, 256, 0, stream>>>(x, xb);
  cvt_w<<<dim3(32, 32, 3), dim3(32, 32), 0, stream>>>(kw, qw, vw, wt);
  gemm_qkv_impl<<<dim3(12, 64), 512, LDSB, stream>>>(xb, wt, q, k, vT);
  gemm_s<<<dim3(8, 8, 8), 512, LDSB, stream>>>(q, k, S);
  softmax_k<<<4096, 256, 0, stream>>>(S);
  gemm_pv<<<dim3(4, 8, 8), 512, LDSB, stream>>>((const ushort*)ws, vT, out);
}

// Round 5
// 301.141 us; speedup vs baseline: 1.1241x; 1.1241x over previous
//
#include <hip/hip_runtime.h>
#include <hip/hip_bf16.h>
#include <stdint.h>

typedef __attribute__((ext_vector_type(4))) float f32x4;
typedef __attribute__((ext_vector_type(8))) short s16x8;

#define BARRIER() asm volatile("s_barrier" ::: "memory")
#define WAITV4()  asm volatile("s_waitcnt vmcnt(4)" ::: "memory")
#define WAITV0()  asm volatile("s_waitcnt vmcnt(0)" ::: "memory")
#define MFMA(a, b, c) __builtin_amdgcn_mfma_f32_16x16x32_bf16((a), (b), (c), 0, 0, 0)

__device__ __forceinline__ ushort f2bf(float f) {
  union { float f; uint32_t u; } v; v.f = f;
  uint32_t r = v.u + 0x7FFFu + ((v.u >> 16) & 1u);
  return (ushort)(r >> 16);
}

__device__ __forceinline__ void gload_lds16(const ushort* g, short* l) {
  __builtin_amdgcn_global_load_lds(
      (const __attribute__((address_space(1))) uint32_t*)g,
      (__attribute__((address_space(3))) uint32_t*)l, 16, 0, 0);
}

// bijective XCD chunk swizzle; valid when nwg % 8 == 0, q = nwg/8
__device__ __forceinline__ int xcd_swz(int flat, int q) {
  return (flat & 7) * q + (flat >> 3);
}

// Stage a 256x64 bf16 tile into LDS. LDS dest linear (global_load_lds
// requirement); T2 swizzle via permuted GLOBAL source 16B-slot:
// phys(r,s) holds global(r, s ^ (r&7)).
__device__ __forceinline__ void stage256(const ushort* __restrict__ g, int ld,
                                         int row0, int k0, short* lbase, int tid) {
  const int w  = tid >> 6;
  const int l  = tid & 63;
  const int lr = l >> 3;
  const int ls = l & 7;
  const ushort* gp = g + (size_t)(row0 + lr) * ld + k0 + ((ls ^ lr) << 3);
  short* lp = lbase + l * 8;
#pragma unroll
  for (int i = 0; i < 4; ++i) {
    const int R0 = w * 32 + i * 8;
    gload_lds16(gp + (size_t)R0 * ld, lp + R0 * 64);
  }
}

// 256x256 tile GEMM core (R3 2-phase, proven): A[M,K]*Bt[N,K]^T, bf16, fp32 acc.
// 512 thr = 8 waves (2M x 4N), wave = 128x64 out = 8x4 frags of 16x16x32.
// Double-buffered LDS (128KB), counted vmcnt(4), raw s_barrier.
__device__ __forceinline__ void gemm_core(
    const ushort* __restrict__ A, int lda, const ushort* __restrict__ Bt, int ldb,
    int m0, int n0, int nk, short* lds, f32x4 acc[8][4])
{
  const int tid  = threadIdx.x;
  const int lane = tid & 63, wid = tid >> 6;
  const int wr = wid >> 2, wc = wid & 3;
  const int fr = lane & 15, kg = lane >> 4;
  const int s0  = (kg ^ (fr & 7)) << 3;        // swizzled slot offset (shorts)
  const int aro = (wr * 128 + fr) * 64;
  const int bro = (wc * 64 + fr) * 64;

  short* Ab0 = lds;            short* Bb0 = lds + 16384;
  short* Ab1 = lds + 32768;    short* Bb1 = lds + 49152;

#pragma unroll
  for (int i = 0; i < 8; ++i)
#pragma unroll
    for (int j = 0; j < 4; ++j)
      acc[i][j] = (f32x4){0.f, 0.f, 0.f, 0.f};

  // prologue: A(0), B(0), B(1) in flight
  stage256(A, lda, m0, 0, Ab0, tid);
  stage256(Bt, ldb, n0, 0, Bb0, tid);
  if (nk > 1) stage256(Bt, ldb, n0, 64, Bb1, tid);

#pragma unroll 1
  for (int X = 0; X < nk; ++X) {
    const int cur = X & 1;
    short* Ac = cur ? Ab1 : Ab0;
    short* Bc = cur ? Bb1 : Bb0;
    short* An = cur ? Ab0 : Ab1;

    // ---- phase alpha: wait tile X resident (keep 4 newest loads in flight)
    if (X + 1 < nk) { WAITV4(); } else { WAITV0(); }
    BARRIER();
    if (X + 1 < nk) stage256(A, lda, m0, (X + 1) * 64, An, tid);   // A(X+1)

    s16x8 b[4][2], a[4][2];
#pragma unroll
    for (int ni = 0; ni < 4; ++ni) {
      b[ni][0] = *(const s16x8*)(Bc + bro + ni * 1024 + s0);
      b[ni][1] = *(const s16x8*)(Bc + bro + ni * 1024 + (s0 ^ 32));
    }
#pragma unroll
    for (int mi = 0; mi < 4; ++mi) {
      a[mi][0] = *(const s16x8*)(Ac + aro + mi * 1024 + s0);
      a[mi][1] = *(const s16x8*)(Ac + aro + mi * 1024 + (s0 ^ 32));
    }
    __builtin_amdgcn_s_setprio(1);
#pragma unroll
    for (int mi = 0; mi < 4; ++mi)
#pragma unroll
      for (int ni = 0; ni < 4; ++ni) {
        acc[mi][ni] = MFMA(a[mi][0], b[ni][0], acc[mi][ni]);
        acc[mi][ni] = MFMA(a[mi][1], b[ni][1], acc[mi][ni]);
      }
    __builtin_amdgcn_s_setprio(0);

    // ---- phase beta: A-half1; B region of buf cur free -> stage B(X+2)
    BARRIER();
    if (X + 2 < nk) stage256(Bt, ldb, n0, (X + 2) * 64, Bc, tid);  // B(X+2)
#pragma unroll
    for (int mi = 0; mi < 4; ++mi) {
      a[mi][0] = *(const s16x8*)(Ac + aro + 4096 + mi * 1024 + s0);
      a[mi][1] = *(const s16x8*)(Ac + aro + 4096 + mi * 1024 + (s0 ^ 32));
    }
    __builtin_amdgcn_s_setprio(1);
#pragma unroll
    for (int mi = 0; mi < 4; ++mi)
#pragma unroll
      for (int ni = 0; ni < 4; ++ni) {
        acc[4 + mi][ni] = MFMA(a[mi][0], b[ni][0], acc[4 + mi][ni]);
        acc[4 + mi][ni] = MFMA(a[mi][1], b[ni][1], acc[4 + mi][ni]);
      }
    __builtin_amdgcn_s_setprio(0);
  }
}

__global__ void cvt_x(const float* __restrict__ x, ushort* __restrict__ xb)
{
  const size_t i = (size_t)(blockIdx.x * 256 + threadIdx.x) * 4;
  const f32x4 t = *(const f32x4*)(x + i);
  uint2 pk;
  pk.x = (uint32_t)f2bf(t[0]) | ((uint32_t)f2bf(t[1]) << 16);
  pk.y = (uint32_t)f2bf(t[2]) | ((uint32_t)f2bf(t[3]) << 16);
  *(uint2*)(xb + i) = pk;
}

// wt[z][n][k] = bf16(w_z[k][n]);  z: 0=q_wei, 1=k_wei, 2=v_wei
__global__ void cvt_w(const float* __restrict__ kw, const float* __restrict__ qw,
                      const float* __restrict__ vw, ushort* __restrict__ wt)
{
  __shared__ float t[32][33];
  const float* w = (blockIdx.z == 0) ? qw : (blockIdx.z == 1) ? kw : vw;
  const int n0 = blockIdx.x * 32, k0 = blockIdx.y * 32;
  t[threadIdx.y][threadIdx.x] = w[(size_t)(k0 + threadIdx.y) * 1024 + n0 + threadIdx.x];
  __syncthreads();
  wt[(size_t)blockIdx.z * 1048576 + (size_t)(n0 + threadIdx.y) * 1024 + k0 + threadIdx.x] =
      f2bf(t[threadIdx.x][threadIdx.y]);
}

// N = 3072 (q|k|v), M = 16384. grid (12, 64).
__global__ __launch_bounds__(512) void gemm_qkv_impl(
    const ushort* __restrict__ xb, const ushort* __restrict__ wt,
    ushort* __restrict__ q, ushort* __restrict__ k, ushort* __restrict__ vT)
{
  extern __shared__ short lds[];
  const int nf = xcd_swz(blockIdx.x + 12 * blockIdx.y, 96);
  const int n0 = (nf % 12) * 256;
  const int m0 = (nf / 12) * 256;
  f32x4 acc[8][4];
  gemm_core(xb, 1024, wt, 1024, m0, n0, 16, lds, acc);

  const int lane = threadIdx.x & 63;
  const int wid = threadIdx.x >> 6;
  const int wr = wid >> 2, wc = wid & 3;
  const int q4 = (lane >> 4) << 2;
  const int fr = lane & 15;
  const int z  = n0 >> 10;                         // uniform per block
  const int cb = (n0 & 1023) + wc * 64 + fr;
  ushort* o = (z == 0) ? q : k;
#pragma unroll
  for (int mi = 0; mi < 8; ++mi)
#pragma unroll
    for (int ni = 0; ni < 4; ++ni)
#pragma unroll
      for (int j = 0; j < 4; ++j) {
        const int r = m0 + wr * 128 + mi * 16 + q4 + j;
        const int c = cb + ni * 16;
        const ushort hv = f2bf(acc[mi][ni][j]);
        if (z < 2) o[(size_t)r * 1024 + c] = hv;
        else       vT[((size_t)(r >> 11) * 1024 + c) * 2048 + (r & 2047)] = hv;
      }
}

// Fused S-GEMM + softmax-exp (no-max trick): writes unnormalized
// P~ = exp(qk/32 - 10) bf16 dense [b][2048][2048], accumulates row sums.
// grid (8 kt, 8 qt, 8 b), causal tile skip.
__global__ __launch_bounds__(512) void gemm_sp(
    const ushort* __restrict__ q, const ushort* __restrict__ k,
    ushort* __restrict__ P, float* __restrict__ sums)
{
  extern __shared__ short lds[];
  float* rowsum = (float*)(lds + 65536);   // [4 wc][256 rows], 4KB past staging
  const int nf = xcd_swz(blockIdx.x + 8 * (blockIdx.y + 8 * blockIdx.z), 64);
  const int kt = nf & 7, qt = (nf >> 3) & 7, b = nf >> 6;
  if (kt > qt) return;  // causal: whole tile masked
  f32x4 acc[8][4];
  const ushort* qb = q + (size_t)b * (2048 * 1024);
  const ushort* kb = k + (size_t)b * (2048 * 1024);
  gemm_core(qb, 1024, kb, 1024, qt * 256, kt * 256, 16, lds, acc);

  const int tid  = threadIdx.x;
  const int lane = tid & 63, wid = tid >> 6;
  const int wr = wid >> 2, wc = wid & 3;
  const int q4 = (lane >> 4) << 2;
  const int fr = lane & 15;
  const int diag = (kt == qt);
  ushort* Pb = P + ((size_t)b << 22);

#pragma unroll
  for (int mi = 0; mi < 8; ++mi)
#pragma unroll
    for (int j = 0; j < 4; ++j) {
      const int rloc = wr * 128 + mi * 16 + q4 + j;      // row in tile
      const int rg   = qt * 256 + rloc;                   // global q index
      float s = 0.f;
#pragma unroll
      for (int ni = 0; ni < 4; ++ni) {
        const int cg = kt * 256 + wc * 64 + ni * 16 + fr; // global k index
        float e = __expf(acc[mi][ni][j] * 0.03125f - 10.f);
        if (diag && cg > rg) e = 0.f;
        s += e;
        Pb[(size_t)rg * 2048 + cg] = f2bf(e);
      }
      // reduce over the 16 fr lanes (this wave's 64-col stripe)
#pragma unroll
      for (int m = 1; m < 16; m <<= 1) s += __shfl_xor(s, m);
      if (fr == 0) rowsum[wc * 256 + rloc] = s;
    }
  __syncthreads();
  if (tid < 256) {
    const float tot = rowsum[tid] + rowsum[256 + tid] + rowsum[512 + tid] + rowsum[768 + tid];
    atomicAdd(&sums[b * 2048 + qt * 256 + tid], tot);
  }
}

// grid (4 ht, 8 qt, 8 b); K truncated causally; out = (P~ . V) / sums[row].
__global__ __launch_bounds__(512) void gemm_pv(
    const ushort* __restrict__ P, const ushort* __restrict__ vT,
    const float* __restrict__ sums, float* __restrict__ out)
{
  extern __shared__ short lds[];
  const int nf = xcd_swz(blockIdx.x + 4 * (blockIdx.y + 8 * blockIdx.z), 32);
  const int ht = nf & 3, qt = (nf >> 2) & 7, b = nf >> 5;
  f32x4 acc[8][4];
  const ushort* Pb = P  + ((size_t)b << 22);           // dense [2048][2048]
  const ushort* Vb = vT + (size_t)b * (1024 * 2048);
  gemm_core(Pb, 2048, Vb, 2048, qt * 256, ht * 256, (qt + 1) * 4, lds, acc);

  float* ob = out + (size_t)b * 2097152;
  const int lane = threadIdx.x & 63;
  const int wid = threadIdx.x >> 6;
  const int wr = wid >> 2, wc = wid & 3;
  const int r0 = qt * 256 + wr * 128 + ((lane >> 4) << 2);
  const int c0 = ht * 256 + wc * 64 + (lane & 15);
#pragma unroll
  for (int mi = 0; mi < 8; ++mi)
#pragma unroll
    for (int j = 0; j < 4; ++j) {
      const int r = r0 + mi * 16 + j;
      const float inv = 1.0f / sums[b * 2048 + r];
#pragma unroll
      for (int ni = 0; ni < 4; ++ni)
        ob[(size_t)r * 1024 + (c0 + ni * 16)] = acc[mi][ni][j] * inv;
    }
}

extern "C" void kernel_launch(void* const* d_in, const int* in_sizes, int n_in,
                              void* d_out, int out_size, void* d_ws, size_t ws_size,
                              hipStream_t stream)
{
  const float* x  = (const float*)d_in[0];
  const float* kw = (const float*)d_in[1];
  const float* qw = (const float*)d_in[2];
  const float* vw = (const float*)d_in[3];
  float* out = (float*)d_out;
  char* ws = (char*)d_ws;

  ushort* xb   = (ushort*)ws;                  // 32MB; aliases P~ (consumed first)
  ushort* P    = (ushort*)ws;                  // 64MB dense bf16 P~ [8][2048][2048]
  float*  sums = (float*)(ws + 67108864);      // 64KB row sums [8][2048]
  ushort* wt   = (ushort*)(ws + 67174400);     // 6MB  transposed bf16 weights [z][n][k]
  ushort* q    = (ushort*)(ws + 73465856);     // 32MB
  ushort* k    = (ushort*)(ws + 107020288);    // 32MB
  ushort* vT   = (ushort*)(ws + 140574720);    // 32MB [B][HS][T]

  const int LDSB  = 131072;           // 128KB dynamic LDS (GEMM cores)
  const int LDSB2 = 131072 + 4096;    // +4KB rowsum for gemm_sp
  hipFuncSetAttribute((const void*)gemm_qkv_impl, hipFuncAttributeMaxDynamicSharedMemorySize, LDSB);
  hipFuncSetAttribute((const void*)gemm_sp,       hipFuncAttributeMaxDynamicSharedMemorySize, LDSB2);
  hipFuncSetAttribute((const void*)gemm_pv,       hipFuncAttributeMaxDynamicSharedMemorySize, LDSB);

  hipMemsetAsync(sums, 0, 8 * 2048 * sizeof(float), stream);
  cvt_x<<<16384, 256, 0, stream>>>(x, xb);
  cvt_w<<<dim3(32, 32, 3), dim3(32, 32), 0, stream>>>(kw, qw, vw, wt);
  gemm_qkv_impl<<<dim3(12, 64), 512, LDSB, stream>>>(xb, wt, q, k, vT);
  gemm_sp<<<dim3(8, 8, 8), 512, LDSB2, stream>>>(q, k, P, sums);
  gemm_pv<<<dim3(4, 8, 8), 512, LDSB, stream>>>(P, vT, sums, out);
}

// Round 6
// 285.981 us; speedup vs baseline: 1.1837x; 1.0530x over previous
//
#include <hip/hip_runtime.h>
#include <hip/hip_bf16.h>
#include <stdint.h>

typedef __attribute__((ext_vector_type(4))) float f32x4;
typedef __attribute__((ext_vector_type(8))) short s16x8;

#define BARRIER() asm volatile("s_barrier" ::: "memory")
#define WAITV4()  asm volatile("s_waitcnt vmcnt(4)" ::: "memory")
#define WAITV0()  asm volatile("s_waitcnt vmcnt(0)" ::: "memory")
#define MFMA(a, b, c) __builtin_amdgcn_mfma_f32_16x16x32_bf16((a), (b), (c), 0, 0, 0)

__device__ __forceinline__ ushort f2bf(float f) {
  union { float f; uint32_t u; } v; v.f = f;
  uint32_t r = v.u + 0x7FFFu + ((v.u >> 16) & 1u);
  return (ushort)(r >> 16);
}

__device__ __forceinline__ void gload_lds16(const ushort* g, short* l) {
  __builtin_amdgcn_global_load_lds(
      (const __attribute__((address_space(1))) uint32_t*)g,
      (__attribute__((address_space(3))) uint32_t*)l, 16, 0, 0);
}

// bijective XCD chunk swizzle; valid when nwg % 8 == 0, q = nwg/8
__device__ __forceinline__ int xcd_swz(int flat, int q) {
  return (flat & 7) * q + (flat >> 3);
}

// Stage a 128x64 bf16 tile into LDS with 256 threads (4 loads/thread).
// LDS dest linear (global_load_lds requirement); T2 swizzle via permuted
// GLOBAL source 16B-slot: phys(r,s) holds global(r, s ^ (r&7)).
__device__ __forceinline__ void stage128(const ushort* __restrict__ g, int ld,
                                         int row0, int k0, short* lbase, int tid) {
  const int w  = tid >> 6;               // 0..3
  const int l  = tid & 63;
  const int lr = l >> 3;                 // row within 8-row group
  const int ls = l & 7;                  // physical 16B slot
  const ushort* gp = g + (size_t)(row0 + lr) * ld + k0 + ((ls ^ lr) << 3);
  short* lp = lbase + l * 8;
#pragma unroll
  for (int i = 0; i < 4; ++i) {
    const int R0 = w * 32 + i * 8;
    gload_lds16(gp + (size_t)R0 * ld, lp + R0 * 64);
  }
}

// 128x128 tile GEMM core: A[M,K]*Bt[N,K]^T, bf16, fp32 acc.
// 256 thr = 4 waves (2M x 2N), wave = 64x64 out = 4x4 frags of 16x16x32.
// 64KB double-buffered LDS -> 2 blocks/CU (cross-block overlap hides stalls).
// R3-proven ledger: counted vmcnt(4), raw s_barrier, stage A(X+1)@alpha,
// B(X+2)@beta.
__device__ __forceinline__ void gemm_core(
    const ushort* __restrict__ A, int lda, const ushort* __restrict__ Bt, int ldb,
    int m0, int n0, int nk, short* lds, f32x4 acc[4][4])
{
  const int tid  = threadIdx.x;
  const int lane = tid & 63, wid = tid >> 6;
  const int wr = wid >> 1, wc = wid & 1;
  const int fr = lane & 15, kg = lane >> 4;
  const int s0  = (kg ^ (fr & 7)) << 3;        // swizzled slot offset (shorts)
  const int aro = (wr * 64 + fr) * 64;
  const int bro = (wc * 64 + fr) * 64;

  short* Ab0 = lds;            short* Bb0 = lds + 8192;
  short* Ab1 = lds + 16384;    short* Bb1 = lds + 24576;

#pragma unroll
  for (int i = 0; i < 4; ++i)
#pragma unroll
    for (int j = 0; j < 4; ++j)
      acc[i][j] = (f32x4){0.f, 0.f, 0.f, 0.f};

  // prologue: A(0), B(0), B(1) in flight (12 loads/thread-group)
  stage128(A, lda, m0, 0, Ab0, tid);
  stage128(Bt, ldb, n0, 0, Bb0, tid);
  if (nk > 1) stage128(Bt, ldb, n0, 64, Bb1, tid);

#pragma unroll 1
  for (int X = 0; X < nk; ++X) {
    const int cur = X & 1;
    short* Ac = cur ? Ab1 : Ab0;
    short* Bc = cur ? Bb1 : Bb0;
    short* An = cur ? Ab0 : Ab1;

    // ---- phase alpha: tile X resident after wait (keep 4 newest in flight)
    if (X + 1 < nk) { WAITV4(); } else { WAITV0(); }
    BARRIER();
    if (X + 1 < nk) stage128(A, lda, m0, (X + 1) * 64, An, tid);   // A(X+1)

    s16x8 b[4][2], a[2][2];
#pragma unroll
    for (int ni = 0; ni < 4; ++ni) {
      b[ni][0] = *(const s16x8*)(Bc + bro + ni * 1024 + s0);
      b[ni][1] = *(const s16x8*)(Bc + bro + ni * 1024 + (s0 ^ 32));
    }
#pragma unroll
    for (int mi = 0; mi < 2; ++mi) {
      a[mi][0] = *(const s16x8*)(Ac + aro + mi * 1024 + s0);
      a[mi][1] = *(const s16x8*)(Ac + aro + mi * 1024 + (s0 ^ 32));
    }
    __builtin_amdgcn_s_setprio(1);
#pragma unroll
    for (int mi = 0; mi < 2; ++mi)
#pragma unroll
      for (int ni = 0; ni < 4; ++ni) {
        acc[mi][ni] = MFMA(a[mi][0], b[ni][0], acc[mi][ni]);
        acc[mi][ni] = MFMA(a[mi][1], b[ni][1], acc[mi][ni]);
      }
    __builtin_amdgcn_s_setprio(0);

    // ---- phase beta: A rows 32-63 of wave panel; stage B(X+2) into Bc
    BARRIER();
    if (X + 2 < nk) stage128(Bt, ldb, n0, (X + 2) * 64, Bc, tid);  // B(X+2)
#pragma unroll
    for (int mi = 0; mi < 2; ++mi) {
      a[mi][0] = *(const s16x8*)(Ac + aro + (2 + mi) * 1024 + s0);
      a[mi][1] = *(const s16x8*)(Ac + aro + (2 + mi) * 1024 + (s0 ^ 32));
    }
    __builtin_amdgcn_s_setprio(1);
#pragma unroll
    for (int mi = 0; mi < 2; ++mi)
#pragma unroll
      for (int ni = 0; ni < 4; ++ni) {
        acc[2 + mi][ni] = MFMA(a[mi][0], b[ni][0], acc[2 + mi][ni]);
        acc[2 + mi][ni] = MFMA(a[mi][1], b[ni][1], acc[2 + mi][ni]);
      }
    __builtin_amdgcn_s_setprio(0);
  }
}

__global__ void cvt_x(const float* __restrict__ x, ushort* __restrict__ xb)
{
  const size_t i = (size_t)(blockIdx.x * 256 + threadIdx.x) * 4;
  const f32x4 t = *(const f32x4*)(x + i);
  uint2 pk;
  pk.x = (uint32_t)f2bf(t[0]) | ((uint32_t)f2bf(t[1]) << 16);
  pk.y = (uint32_t)f2bf(t[2]) | ((uint32_t)f2bf(t[3]) << 16);
  *(uint2*)(xb + i) = pk;
}

// wt[z][n][k] = bf16(w_z[k][n]);  z: 0=q_wei, 1=k_wei, 2=v_wei
__global__ void cvt_w(const float* __restrict__ kw, const float* __restrict__ qw,
                      const float* __restrict__ vw, ushort* __restrict__ wt)
{
  __shared__ float t[32][33];
  const float* w = (blockIdx.z == 0) ? qw : (blockIdx.z == 1) ? kw : vw;
  const int n0 = blockIdx.x * 32, k0 = blockIdx.y * 32;
  t[threadIdx.y][threadIdx.x] = w[(size_t)(k0 + threadIdx.y) * 1024 + n0 + threadIdx.x];
  __syncthreads();
  wt[(size_t)blockIdx.z * 1048576 + (size_t)(n0 + threadIdx.y) * 1024 + k0 + threadIdx.x] =
      f2bf(t[threadIdx.x][threadIdx.y]);
}

// N = 3072 (q|k|v), M = 16384. grid (24, 128) = 3072 blocks, q = 384.
__global__ __launch_bounds__(256) void gemm_qkv_impl(
    const ushort* __restrict__ xb, const ushort* __restrict__ wt,
    ushort* __restrict__ q, ushort* __restrict__ k, ushort* __restrict__ vT)
{
  extern __shared__ short lds[];
  const int nf = xcd_swz(blockIdx.x + 24 * blockIdx.y, 384);
  const int n0 = (nf % 24) * 128;
  const int m0 = (nf / 24) * 128;
  f32x4 acc[4][4];
  gemm_core(xb, 1024, wt, 1024, m0, n0, 16, lds, acc);

  const int lane = threadIdx.x & 63;
  const int wid = threadIdx.x >> 6;
  const int wr = wid >> 1, wc = wid & 1;
  const int q4 = (lane >> 4) << 2;
  const int fr = lane & 15;
  const int z  = n0 >> 10;                         // uniform per block
  const int cb = (n0 & 1023) + wc * 64 + fr;
  ushort* o = (z == 0) ? q : k;
#pragma unroll
  for (int mi = 0; mi < 4; ++mi)
#pragma unroll
    for (int ni = 0; ni < 4; ++ni)
#pragma unroll
      for (int j = 0; j < 4; ++j) {
        const int r = m0 + wr * 64 + mi * 16 + q4 + j;
        const int c = cb + ni * 16;
        const ushort hv = f2bf(acc[mi][ni][j]);
        if (z < 2) o[(size_t)r * 1024 + c] = hv;
        else       vT[((size_t)(r >> 11) * 1024 + c) * 2048 + (r & 2047)] = hv;
      }
}

// Fused S-GEMM + softmax-exp (no-max trick): writes unnormalized
// P~ = exp(qk/32 - 10) bf16 dense [b][2048][2048], accumulates row sums.
// grid (16 kt, 16 qt, 8 b) = 2048 blocks, q = 256; causal tile skip.
__global__ __launch_bounds__(256) void gemm_sp(
    const ushort* __restrict__ q, const ushort* __restrict__ k,
    ushort* __restrict__ P, float* __restrict__ sums)
{
  extern __shared__ short lds[];
  float* rowsum = (float*)(lds + 32768);   // [2 wc][128 rows], 1KB past staging
  const int nf = xcd_swz(blockIdx.x + 16 * (blockIdx.y + 16 * blockIdx.z), 256);
  const int kt = nf & 15, qt = (nf >> 4) & 15, b = nf >> 8;
  if (kt > qt) return;  // causal: whole tile masked
  f32x4 acc[4][4];
  const ushort* qb = q + (size_t)b * (2048 * 1024);
  const ushort* kb = k + (size_t)b * (2048 * 1024);
  gemm_core(qb, 1024, kb, 1024, qt * 128, kt * 128, 16, lds, acc);

  const int tid  = threadIdx.x;
  const int lane = tid & 63, wid = tid >> 6;
  const int wr = wid >> 1, wc = wid & 1;
  const int q4 = (lane >> 4) << 2;
  const int fr = lane & 15;
  const int diag = (kt == qt);
  ushort* Pb = P + ((size_t)b << 22);

#pragma unroll
  for (int mi = 0; mi < 4; ++mi)
#pragma unroll
    for (int j = 0; j < 4; ++j) {
      const int rloc = wr * 64 + mi * 16 + q4 + j;       // row in tile
      const int rg   = qt * 128 + rloc;                   // global q index
      float s = 0.f;
#pragma unroll
      for (int ni = 0; ni < 4; ++ni) {
        const int cg = kt * 128 + wc * 64 + ni * 16 + fr; // global k index
        float e = __expf(acc[mi][ni][j] * 0.03125f - 10.f);
        if (diag && cg > rg) e = 0.f;
        s += e;
        Pb[(size_t)rg * 2048 + cg] = f2bf(e);
      }
      // reduce over the 16 fr lanes (this wave's 64-col stripe)
#pragma unroll
      for (int m = 1; m < 16; m <<= 1) s += __shfl_xor(s, m);
      if (fr == 0) rowsum[wc * 128 + rloc] = s;
    }
  __syncthreads();
  if (tid < 128) {
    const float tot = rowsum[tid] + rowsum[128 + tid];
    atomicAdd(&sums[b * 2048 + qt * 128 + tid], tot);
  }
}

// grid (8 ht, 16 qt, 8 b) = 1024 blocks, q = 128; K truncated causally;
// out = (P~ . V) / sums[row].
__global__ __launch_bounds__(256) void gemm_pv(
    const ushort* __restrict__ P, const ushort* __restrict__ vT,
    const float* __restrict__ sums, float* __restrict__ out)
{
  extern __shared__ short lds[];
  const int nf = xcd_swz(blockIdx.x + 8 * (blockIdx.y + 16 * blockIdx.z), 128);
  const int ht = nf & 7, qt = (nf >> 3) & 15, b = nf >> 7;
  f32x4 acc[4][4];
  const ushort* Pb = P  + ((size_t)b << 22);           // dense [2048][2048]
  const ushort* Vb = vT + (size_t)b * (1024 * 2048);
  gemm_core(Pb, 2048, Vb, 2048, qt * 128, ht * 128, (qt + 1) * 2, lds, acc);

  float* ob = out + (size_t)b * 2097152;
  const int lane = threadIdx.x & 63;
  const int wid = threadIdx.x >> 6;
  const int wr = wid >> 1, wc = wid & 1;
  const int r0 = qt * 128 + wr * 64 + ((lane >> 4) << 2);
  const int c0 = ht * 128 + wc * 64 + (lane & 15);
#pragma unroll
  for (int mi = 0; mi < 4; ++mi)
#pragma unroll
    for (int j = 0; j < 4; ++j) {
      const int r = r0 + mi * 16 + j;
      const float inv = 1.0f / sums[b * 2048 + r];
#pragma unroll
      for (int ni = 0; ni < 4; ++ni)
        ob[(size_t)r * 1024 + (c0 + ni * 16)] = acc[mi][ni][j] * inv;
    }
}

extern "C" void kernel_launch(void* const* d_in, const int* in_sizes, int n_in,
                              void* d_out, int out_size, void* d_ws, size_t ws_size,
                              hipStream_t stream)
{
  const float* x  = (const float*)d_in[0];
  const float* kw = (const float*)d_in[1];
  const float* qw = (const float*)d_in[2];
  const float* vw = (const float*)d_in[3];
  float* out = (float*)d_out;
  char* ws = (char*)d_ws;

  ushort* xb   = (ushort*)ws;                  // 32MB; aliases P~ (consumed first)
  ushort* P    = (ushort*)ws;                  // 64MB dense bf16 P~ [8][2048][2048]
  float*  sums = (float*)(ws + 67108864);      // 64KB row sums [8][2048]
  ushort* wt   = (ushort*)(ws + 67174400);     // 6MB  transposed bf16 weights [z][n][k]
  ushort* q    = (ushort*)(ws + 73465856);     // 32MB
  ushort* k    = (ushort*)(ws + 107020288);    // 32MB
  ushort* vT   = (ushort*)(ws + 140574720);    // 32MB [B][HS][T]

  const int LDSB  = 65536;            // 64KB dynamic LDS -> 2 blocks/CU
  const int LDSB2 = 65536 + 1024;     // +1KB rowsum for gemm_sp
  hipFuncSetAttribute((const void*)gemm_qkv_impl, hipFuncAttributeMaxDynamicSharedMemorySize, LDSB);
  hipFuncSetAttribute((const void*)gemm_sp,       hipFuncAttributeMaxDynamicSharedMemorySize, LDSB2);
  hipFuncSetAttribute((const void*)gemm_pv,       hipFuncAttributeMaxDynamicSharedMemorySize, LDSB);

  hipMemsetAsync(sums, 0, 8 * 2048 * sizeof(float), stream);
  cvt_x<<<16384, 256, 0, stream>>>(x, xb);
  cvt_w<<<dim3(32, 32, 3), dim3(32, 32), 0, stream>>>(kw, qw, vw, wt);
  gemm_qkv_impl<<<dim3(24, 128), 256, LDSB, stream>>>(xb, wt, q, k, vT);
  gemm_sp<<<dim3(16, 16, 8), 256, LDSB2, stream>>>(q, k, P, sums);
  gemm_pv<<<dim3(8, 16, 8), 256, LDSB, stream>>>(P, vT, sums, out);
}